// Round 1
// baseline (856.582 us; speedup 1.0000x reference)
//
#include <hip/hip_runtime.h>
#include <math.h>

#define T_LEN   8000
#define CHUNK   32
#define NTHREADS 256
#define NCHUNK  (T_LEN / CHUNK)   // 250
#define NVEC4   (T_LEN / 4)       // 2000
#define FLOORV  1e-6f

// One block per (b,c) row. Chunked parallel scan for the EMA recurrence:
//   ema[t] = w*x[t] + q*ema[t-1],  q = 1-w,  ema[-1] = x[0]
// Each thread owns a 32-elem chunk -> affine map e_out = A + D*e_in (D = q^32).
// Hillis-Steele scan over 256 maps composes carries exactly, then a second
// pass replays each chunk with the right carry-in and applies the PCEN
// pointwise math.
__global__ __launch_bounds__(NTHREADS, 4) void pcen_kernel(
    const float* __restrict__ x,
    const float* __restrict__ alpha,
    const float* __restrict__ delta,
    const float* __restrict__ root,
    const float* __restrict__ emaw,
    float* __restrict__ out,
    int C)
{
    // Skewed LDS row: element j lives at j + j/32  -> chunk reads are
    // bank-conflict-free (bank = (t+i)%32, 2 lanes/bank for wave64 = free).
    __shared__ float sx[T_LEN + NCHUNK];   // 8250 floats
    __shared__ float sA[NTHREADS];
    __shared__ float sD[NTHREADS];

    const int row = blockIdx.x;
    const int c   = row % C;
    const int tid = threadIdx.x;

    const float a  = fminf(alpha[c], 1.0f);
    const float d  = delta[c];
    const float rt = fmaxf(root[c], 1.0f);
    const float r  = 1.0f / rt;
    const float w  = fminf(fmaxf(emaw[c], 0.0f), 1.0f);
    const float q  = 1.0f - w;
    const float dr = __powf(d, r);

    // ---- stage row into LDS (coalesced float4 loads) ----
    const float4* xrow = (const float4*)(x + (size_t)row * T_LEN);
    #pragma unroll
    for (int it = 0; it < 8; ++it) {
        int f = it * NTHREADS + tid;
        if (f < NVEC4) {
            float4 v = xrow[f];
            int j = f * 4;
            int s = j + (j >> 5);      // skew (all 4 elems in same chunk)
            sx[s + 0] = v.x; sx[s + 1] = v.y; sx[s + 2] = v.z; sx[s + 3] = v.w;
        }
    }
    __syncthreads();

    const float x0 = sx[0];            // ema init; read BEFORE pass 2 overwrites

    // ---- pass 1: per-chunk affine reduction (A, D) ----
    float A = 0.0f, D = 1.0f;
    if (tid < NCHUNK) {
        const int base = tid * (CHUNK + 1);   // 33*tid (skewed chunk start)
        float acc = 0.0f;
        #pragma unroll
        for (int i = 0; i < CHUNK; ++i)
            acc = fmaf(q, acc, w * sx[base + i]);
        A = acc;
        float q2 = q * q, q4 = q2 * q2, q8 = q4 * q4, q16 = q8 * q8;
        D = q16 * q16;                 // q^32
    }
    sA[tid] = A;
    sD[tid] = D;
    __syncthreads();

    // ---- inclusive Hillis-Steele scan of affine maps ----
    // combine(left, self): A = A_s + D_s*A_l ; D = D_s*D_l
    #pragma unroll
    for (int off = 1; off < NTHREADS; off <<= 1) {
        float aS = sA[tid], dS = sD[tid];
        float aL = 0.0f, dL = 1.0f;
        if (tid >= off) { aL = sA[tid - off]; dL = sD[tid - off]; }
        __syncthreads();
        if (tid >= off) {
            sA[tid] = fmaf(dS, aL, aS);
            sD[tid] = dS * dL;
        }
        __syncthreads();
    }

    // ---- pass 2: replay chunk with exact carry-in, apply PCEN pointwise ----
    if (tid < NCHUNK) {
        float e = (tid == 0) ? x0 : fmaf(sD[tid - 1], x0, sA[tid - 1]);
        const int base = tid * (CHUNK + 1);
        #pragma unroll
        for (int i = 0; i < CHUNK; ++i) {
            float xv = sx[base + i];
            e = fmaf(q, e, w * xv);
            float p  = __powf(FLOORV + e, a);      // (floor+ema)^a
            float b2 = xv / p + d;
            float o  = __powf(b2, r) - dr;
            sx[base + i] = o;                      // overwrite in place
        }
    }
    __syncthreads();

    // ---- store (coalesced float4) ----
    float4* orow = (float4*)(out + (size_t)row * T_LEN);
    #pragma unroll
    for (int it = 0; it < 8; ++it) {
        int f = it * NTHREADS + tid;
        if (f < NVEC4) {
            int j = f * 4;
            int s = j + (j >> 5);
            float4 v;
            v.x = sx[s + 0]; v.y = sx[s + 1]; v.z = sx[s + 2]; v.w = sx[s + 3];
            orow[f] = v;
        }
    }
}

extern "C" void kernel_launch(void* const* d_in, const int* in_sizes, int n_in,
                              void* d_out, int out_size, void* d_ws, size_t ws_size,
                              hipStream_t stream) {
    const float* x     = (const float*)d_in[0];
    const float* alpha = (const float*)d_in[1];
    const float* delta = (const float*)d_in[2];
    const float* root  = (const float*)d_in[3];
    const float* emaw  = (const float*)d_in[4];
    float* out = (float*)d_out;

    const int C    = in_sizes[1];              // 64
    const int rows = in_sizes[0] / T_LEN;      // B*C = 8192

    pcen_kernel<<<rows, NTHREADS, 0, stream>>>(x, alpha, delta, root, emaw, out, C);
}

// Round 2
// 437.837 us; speedup vs baseline: 1.9564x; 1.9564x over previous
//
#include <hip/hip_runtime.h>
#include <math.h>

#define T_LEN   8000
#define CHUNK   32
#define NTHREADS 256
#define NCHUNK  (T_LEN / CHUNK)   // 250
#define NVEC4   (T_LEN / 4)       // 2000
#define FLOORV  1e-6f

// One block per (b,c) row. Chunked parallel scan for the EMA recurrence:
//   ema[t] = w*x[t] + q*ema[t-1],  q = 1-w,  ema[-1] = x[0]
// Pointwise PCEN math uses raw v_log_f32/v_exp_f32 (single HW instrs):
//   x/(f+ema)^a = x * exp2(-a*log2(f+ema))   -- division folded into exponent.
// R1 post-mortem: __powf (OCML pow, ~80 instrs) + IEEE div made the kernel
// VALU-issue-bound (VALUBusy 108%, 627us). Fast path cuts ~150 -> ~8
// VALU instrs/element; accuracy headroom is ~30x the threshold.
__global__ __launch_bounds__(NTHREADS, 4) void pcen_kernel(
    const float* __restrict__ x,
    const float* __restrict__ alpha,
    const float* __restrict__ delta,
    const float* __restrict__ root,
    const float* __restrict__ emaw,
    float* __restrict__ out,
    int C)
{
    // Skewed LDS row: element j lives at j + j/32 -> chunk reads hit
    // bank (t+i)%32, 2 lanes/bank for wave64 = conflict-free (m136).
    __shared__ float sx[T_LEN + NCHUNK];   // 8250 floats
    __shared__ float sA[NTHREADS];
    __shared__ float sD[NTHREADS];

    const int row = blockIdx.x;
    const int c   = row % C;
    const int tid = threadIdx.x;

    const float a  = fminf(alpha[c], 1.0f);
    const float d  = delta[c];
    const float rt = fmaxf(root[c], 1.0f);
    const float r  = 1.0f / rt;
    const float w  = fminf(fmaxf(emaw[c], 0.0f), 1.0f);
    const float q  = 1.0f - w;
    const float na = -a;
    // d^r via hw log/exp (d >= 0; log2(0) = -inf -> exp2 -> 0, still correct)
    const float dr = __builtin_amdgcn_exp2f(r * __builtin_amdgcn_logf(d));

    // ---- stage row into LDS (coalesced float4 loads) ----
    const float4* xrow = (const float4*)(x + (size_t)row * T_LEN);
    #pragma unroll
    for (int it = 0; it < 8; ++it) {
        int f = it * NTHREADS + tid;
        if (f < NVEC4) {
            float4 v = xrow[f];
            int j = f * 4;
            int s = j + (j >> 5);      // skew (all 4 elems in same chunk)
            sx[s + 0] = v.x; sx[s + 1] = v.y; sx[s + 2] = v.z; sx[s + 3] = v.w;
        }
    }
    __syncthreads();

    const float x0 = sx[0];            // ema init; read BEFORE pass 2 overwrites

    // ---- pass 1: per-chunk affine reduction (A, D=q^32) ----
    float A = 0.0f, D = 1.0f;
    if (tid < NCHUNK) {
        const int base = tid * (CHUNK + 1);   // 33*tid (skewed chunk start)
        float acc = 0.0f;
        #pragma unroll
        for (int i = 0; i < CHUNK; ++i)
            acc = fmaf(q, acc, w * sx[base + i]);
        A = acc;
        float q2 = q * q, q4 = q2 * q2, q8 = q4 * q4, q16 = q8 * q8;
        D = q16 * q16;                 // q^32
    }
    sA[tid] = A;
    sD[tid] = D;
    __syncthreads();

    // ---- inclusive Hillis-Steele scan of affine maps ----
    #pragma unroll
    for (int off = 1; off < NTHREADS; off <<= 1) {
        float aS = sA[tid], dS = sD[tid];
        float aL = 0.0f, dL = 1.0f;
        if (tid >= off) { aL = sA[tid - off]; dL = sD[tid - off]; }
        __syncthreads();
        if (tid >= off) {
            sA[tid] = fmaf(dS, aL, aS);
            sD[tid] = dS * dL;
        }
        __syncthreads();
    }

    // ---- pass 2: replay chunk with exact carry-in, apply PCEN pointwise ----
    if (tid < NCHUNK) {
        float e = (tid == 0) ? x0 : fmaf(sD[tid - 1], x0, sA[tid - 1]);
        const int base = tid * (CHUNK + 1);
        #pragma unroll
        for (int i = 0; i < CHUNK; ++i) {
            float xv = sx[base + i];
            e = fmaf(q, e, w * xv);
            // u = (floor+ema)^(-a)
            float u  = __builtin_amdgcn_exp2f(na * __builtin_amdgcn_logf(FLOORV + e));
            float b2 = fmaf(xv, u, d);             // x*u + d  (b2 > 0)
            float o  = __builtin_amdgcn_exp2f(r * __builtin_amdgcn_logf(b2)) - dr;
            sx[base + i] = o;                      // overwrite in place
        }
    }
    __syncthreads();

    // ---- store (coalesced float4) ----
    float4* orow = (float4*)(out + (size_t)row * T_LEN);
    #pragma unroll
    for (int it = 0; it < 8; ++it) {
        int f = it * NTHREADS + tid;
        if (f < NVEC4) {
            int j = f * 4;
            int s = j + (j >> 5);
            float4 v;
            v.x = sx[s + 0]; v.y = sx[s + 1]; v.z = sx[s + 2]; v.w = sx[s + 3];
            orow[f] = v;
        }
    }
}

extern "C" void kernel_launch(void* const* d_in, const int* in_sizes, int n_in,
                              void* d_out, int out_size, void* d_ws, size_t ws_size,
                              hipStream_t stream) {
    const float* x     = (const float*)d_in[0];
    const float* alpha = (const float*)d_in[1];
    const float* delta = (const float*)d_in[2];
    const float* root  = (const float*)d_in[3];
    const float* emaw  = (const float*)d_in[4];
    float* out = (float*)d_out;

    const int C    = in_sizes[1];              // 64
    const int rows = in_sizes[0] / T_LEN;      // B*C = 8192

    pcen_kernel<<<rows, NTHREADS, 0, stream>>>(x, alpha, delta, root, emaw, out, C);
}